// Round 2
// baseline (204.328 us; speedup 1.0000x reference)
//
#include <hip/hip_runtime.h>

// AWGN index channel: rx = idx XOR bitflip-mask(u < BER), codebook gather,
// concat [fine | coarse] per batch row. Exact integer semantics -> absmax 0.
//
// R2: barrier-free. Each wave handles 2 symbols (32 lanes x float4 = 512 B
// each). Lanes 0-8 / 32-40 each load one uniform; a single 64-bit __ballot
// produces both flip masks. No LDS, no __syncthreads, grid-stride loop with
// exactly 32 waves/CU occupancy (2048 blocks x 256 thr on 256 CUs).

constexpr int   BITS       = 9;
constexpr float BER        = 0.02f;
constexpr int   Bn         = 64;
constexpr int   HC = 32, WC = 32, HF = 64, WF = 64, D = 128;
constexpr int   NF         = Bn * HF * WF;     // 262144 fine symbols
constexpr int   NC         = Bn * HC * WC;     // 65536 coarse symbols
constexpr int   NTOT       = NF + NC;          // 327680
constexpr int   FINE_ROW   = HF * WF * D;      // 524288 floats
constexpr int   COARSE_ROW = HC * WC * D;      // 131072 floats
constexpr int   ROW        = FINE_ROW + COARSE_ROW; // 655360 floats / batch row

constexpr int   GRID  = 2048;                  // 8 blocks/CU * 256 CUs
constexpr int   SYMS_PER_BLK_ITER = 8;         // 4 waves * 2 symbols
constexpr int   ITERS = NTOT / (SYMS_PER_BLK_ITER * GRID);  // 20, exact

__global__ __launch_bounds__(256) void chan_gather_kernel(
    const int*   __restrict__ idx_c,
    const int*   __restrict__ idx_f,
    const float* __restrict__ cb_c,
    const float* __restrict__ cb_f,
    const float* __restrict__ u_c,
    const float* __restrict__ u_f,
    float*       __restrict__ out)
{
    const int t          = threadIdx.x;
    const int sym_in_blk = t >> 5;        // 0..7
    const int half       = (t >> 5) & 1;  // which symbol within the wave
    const int lane32     = t & 31;        // float4 slot within the 128-f row

    #pragma unroll
    for (int it = 0; it < ITERS; ++it) {
        const int c = it * GRID + blockIdx.x;          // chunk of 8 symbols
        const int i = c * SYMS_PER_BLK_ITER + sym_in_blk;

        // NF % 8 == 0 -> every chunk is purely fine or purely coarse
        // (branch is block-uniform).
        const float* u;  const int* idxp;  const float* cb;
        int off, local;
        if (i < NF) {
            const int b = i >> 12, rem = i & 4095;     // / , % (HF*WF)
            off   = b * ROW + rem * D;
            u     = u_f;  idxp = idx_f;  cb = cb_f;
            local = i;
        } else {
            const int j = i - NF;
            const int b = j >> 10, rem = j & 1023;     // / , % (HC*WC)
            off   = b * ROW + FINE_ROW + rem * D;
            u     = u_c;  idxp = idx_c;  cb = cb_c;
            local = j;
        }

        // Lane-parallel bit flips: lanes 0-8 of each half-wave read one
        // uniform each; one 64-bit ballot yields both symbols' masks.
        bool pred = false;
        if (lane32 < BITS)
            pred = u[(size_t)local * BITS + lane32] < BER;
        const unsigned long long m = __ballot(pred);
        const int flip = (int)((m >> (half << 5)) & 511u);

        // idx load: all 32 lanes of the half-wave hit the same dword
        // (hardware broadcast).
        const int row = (idxp[local] ^ flip) & 511;

        // 512 B L2-resident gather + 512 B contiguous store per symbol
        // (1 KB contiguous per wave, 4 KB per block-iteration).
        const float4 val = ((const float4*)(cb + row * D))[lane32];
        ((float4*)(out + off))[lane32] = val;
    }
}

extern "C" void kernel_launch(void* const* d_in, const int* in_sizes, int n_in,
                              void* d_out, int out_size, void* d_ws, size_t ws_size,
                              hipStream_t stream) {
    const int*   idx_c = (const int*)  d_in[0];
    const int*   idx_f = (const int*)  d_in[1];
    const float* cb_c  = (const float*)d_in[2];
    const float* cb_f  = (const float*)d_in[3];
    const float* u_c   = (const float*)d_in[4];
    const float* u_f   = (const float*)d_in[5];
    float*       out   = (float*)d_out;

    chan_gather_kernel<<<GRID, 256, 0, stream>>>(
        idx_c, idx_f, cb_c, cb_f, u_c, u_f, out);
}

// Round 3
// 184.507 us; speedup vs baseline: 1.1074x; 1.1074x over previous
//
#include <hip/hip_runtime.h>

// AWGN index channel: rx = idx XOR bitflip-mask(u < BER), codebook gather,
// concat [fine | coarse] per batch row. Exact integer semantics -> absmax 0.
//
// R3: two-kernel decoupling. Kernel A computes all 327680 received indices
// into d_ws (coalesced, one thread per symbol) so Kernel B's gather address
// depends only on a tiny L2-warm broadcast read -- B becomes a pure
// 168 MB write stream (the HBM floor, ~29 us) instead of dragging the
// u-load -> ballot -> gather dependency chain through every store.

constexpr int   BITS       = 9;
constexpr float BER        = 0.02f;
constexpr int   Bn         = 64;
constexpr int   HC = 32, WC = 32, HF = 64, WF = 64, D = 128;
constexpr int   NF         = Bn * HF * WF;     // 262144 fine symbols
constexpr int   NC         = Bn * HC * WC;     // 65536 coarse symbols
constexpr int   NTOT       = NF + NC;          // 327680
constexpr int   FINE_ROW   = HF * WF * D;      // 524288 floats
constexpr int   COARSE_ROW = HC * WC * D;      // 131072 floats
constexpr int   ROW        = FINE_ROW + COARSE_ROW; // 655360 floats / batch row

// ---------------- Kernel A: bit-flip channel -> rx indices ----------------
// One thread per symbol. NF = 1024 blocks exactly, so the fine/coarse branch
// is block-uniform. 9 scalar loads per thread (36 B span), all 64 lanes
// active. Traffic: 11.8 MB read + 1.3 MB write.
__global__ __launch_bounds__(256) void flip_kernel(
    const int*   __restrict__ idx_c,
    const int*   __restrict__ idx_f,
    const float* __restrict__ u_c,
    const float* __restrict__ u_f,
    int*         __restrict__ rx)
{
    const int s = blockIdx.x * 256 + threadIdx.x;   // [0, NTOT)
    const float* u;  const int* idxp;  int local;
    if (s < NF) { u = u_f; idxp = idx_f; local = s; }
    else        { u = u_c; idxp = idx_c; local = s - NF; }
    const float* up = u + (size_t)local * BITS;
    int flip = 0;
    #pragma unroll
    for (int k = 0; k < BITS; ++k)
        flip |= (up[k] < BER) ? (1 << k) : 0;
    rx[s] = (idxp[local] ^ flip) & 511;             // clip is a no-op
}

// ---------------- Kernel B: codebook gather + concat store ----------------
// Half-wave (32 lanes x float4 = 512 B) per symbol; wave stores 1 KB
// contiguous, block 4 KB. Chunks of 8 symbols are purely fine or purely
// coarse (NF % 8 == 0). Unroll capped at 2 to keep VGPRs low -> 32 waves/CU.
constexpr int GRID  = 2048;                         // 8 blocks/CU
constexpr int ITERS = NTOT / (8 * GRID);            // 20, exact

__global__ __launch_bounds__(256) void gather_kernel(
    const float* __restrict__ cb_c,
    const float* __restrict__ cb_f,
    const int*   __restrict__ rx,
    float*       __restrict__ out)
{
    const int t          = threadIdx.x;
    const int sym_in_blk = t >> 5;                  // 0..7
    const int lane32     = t & 31;                  // float4 slot in 128-f row

    #pragma unroll 2
    for (int it = 0; it < ITERS; ++it) {
        const int i = (it * GRID + blockIdx.x) * 8 + sym_in_blk;
        const int row = rx[i];                      // broadcast, L2-warm

        const float* cb;  int off;
        if (i < NF) {
            const int b = i >> 12, rem = i & 4095;  // / , % (HF*WF)
            off = b * ROW + rem * D;                cb = cb_f;
        } else {
            const int j = i - NF;
            const int b = j >> 10, rem = j & 1023;  // / , % (HC*WC)
            off = b * ROW + FINE_ROW + rem * D;     cb = cb_c;
        }

        const float4 val = ((const float4*)(cb + row * D))[lane32];  // L2 hit
        ((float4*)(out + off))[lane32] = val;       // 512 B contiguous/symbol
    }
}

extern "C" void kernel_launch(void* const* d_in, const int* in_sizes, int n_in,
                              void* d_out, int out_size, void* d_ws, size_t ws_size,
                              hipStream_t stream) {
    const int*   idx_c = (const int*)  d_in[0];
    const int*   idx_f = (const int*)  d_in[1];
    const float* cb_c  = (const float*)d_in[2];
    const float* cb_f  = (const float*)d_in[3];
    const float* u_c   = (const float*)d_in[4];
    const float* u_f   = (const float*)d_in[5];
    float*       out   = (float*)d_out;
    int*         rx    = (int*)d_ws;                // 1.3 MB of scratch

    flip_kernel<<<NTOT / 256, 256, 0, stream>>>(idx_c, idx_f, u_c, u_f, rx);
    gather_kernel<<<GRID, 256, 0, stream>>>(cb_c, cb_f, rx, out);
}